// Round 1
// baseline (138.219 us; speedup 1.0000x reference)
//
#include <hip/hip_runtime.h>
#include <hip/hip_bf16.h>

#define NUM_MOL 1024
#define KEHALF 7.199822675975274f
#define RCUT 10.0f

__device__ __forceinline__ float softplus_f(float x) {
    // jax.nn.softplus = log1p(exp(x)); guard overflow
    return (x > 20.0f) ? x : log1pf(__expf(x));
}

// ---------------------------------------------------------------------------
// Prep: per-atom packed table  float4{ Z, Z^softplus(apow), mol(bits), 0 }
// ---------------------------------------------------------------------------
__global__ void zbl_prep_kernel(const float* __restrict__ Z,
                                const int* __restrict__ idx_m,
                                const float* __restrict__ apow,
                                float4* __restrict__ atab, int N) {
    int n = blockIdx.x * blockDim.x + threadIdx.x;
    if (n >= N) return;
    float p = softplus_f(apow[0]);
    float z = Z[n];
    float zp = __powf(z, p);          // z >= 1 always (atomic numbers)
    atab[n] = make_float4(z, zp, __int_as_float(idx_m[n]), 0.0f);
}

// ---------------------------------------------------------------------------
// Main edge kernel (precomputed atom table path)
// ---------------------------------------------------------------------------
__global__ __launch_bounds__(256) void zbl_edge_kernel(
    const float* __restrict__ r_ij,
    const int* __restrict__ idx_i,
    const int* __restrict__ idx_j,
    const float4* __restrict__ atab,
    const float* __restrict__ adiv,
    const float* __restrict__ a_vector,
    const float* __restrict__ c_vector,
    float* __restrict__ y, int E)
{
    __shared__ float bins[NUM_MOL];
    for (int b = threadIdx.x; b < NUM_MOL; b += blockDim.x) bins[b] = 0.0f;
    __syncthreads();

    // Uniform scalar parameters (tiny arrays, cache-resident)
    const float sp_adiv = softplus_f(adiv[0]);
    const float sa0 = softplus_f(a_vector[0]);
    const float sa1 = softplus_f(a_vector[1]);
    const float sa2 = softplus_f(a_vector[2]);
    const float sa3 = softplus_f(a_vector[3]);
    float c0 = softplus_f(c_vector[0]);
    float c1 = softplus_f(c_vector[1]);
    float c2 = softplus_f(c_vector[2]);
    float c3 = softplus_f(c_vector[3]);
    const float cs = fabsf(c0) + fabsf(c1) + fabsf(c2) + fabsf(c3);
    const float cinv = 1.0f / cs;
    c0 *= cinv; c1 *= cinv; c2 *= cinv; c3 *= cinv;

    const int stride = gridDim.x * blockDim.x;
    for (int e = blockIdx.x * blockDim.x + threadIdx.x; e < E; e += stride) {
        const int i = idx_i[e];
        const int j = idx_j[e];
        const float4 ai = atab[i];
        const float4 aj = atab[j];
        const float x  = r_ij[3 * e + 0];
        const float yy = r_ij[3 * e + 1];
        const float zz = r_ij[3 * e + 2];
        const float d = sqrtf(x * x + yy * yy + zz * zz);

        // PhysNet cutoff: 1 - 6u^5 + 15u^4 - 10u^3 for d < rc else 0
        const float u = d * (1.0f / RCUT);
        const float u3 = u * u * u;
        float fc = 1.0f + u3 * (-10.0f + u * (15.0f - 6.0f * u));
        fc = (d < RCUT) ? fc : 0.0f;

        const float a = (ai.y + aj.y) * sp_adiv;     // (z_i^p + z_j^p) * sp(adiv)
        const float ad = a * d;
        const float ft = c0 * __expf(-sa0 * ad) + c1 * __expf(-sa1 * ad)
                       + c2 * __expf(-sa2 * ad) + c3 * __expf(-sa3 * ad);

        const float ee = KEHALF * ft * fc * ai.x * aj.x / d;
        atomicAdd(&bins[__float_as_int(ai.z)], ee);
    }

    __syncthreads();
    for (int b = threadIdx.x; b < NUM_MOL; b += blockDim.x) {
        const float v = bins[b];
        if (v != 0.0f) atomicAdd(&y[b], v);
    }
}

// ---------------------------------------------------------------------------
// Fallback edge kernel (no workspace): gather Z/idx_m directly, pow per edge
// ---------------------------------------------------------------------------
__global__ __launch_bounds__(256) void zbl_edge_kernel_nows(
    const float* __restrict__ r_ij,
    const int* __restrict__ idx_i,
    const int* __restrict__ idx_j,
    const float* __restrict__ Z,
    const int* __restrict__ idx_m,
    const float* __restrict__ adiv,
    const float* __restrict__ apow,
    const float* __restrict__ a_vector,
    const float* __restrict__ c_vector,
    float* __restrict__ y, int E)
{
    __shared__ float bins[NUM_MOL];
    for (int b = threadIdx.x; b < NUM_MOL; b += blockDim.x) bins[b] = 0.0f;
    __syncthreads();

    const float sp_apow = softplus_f(apow[0]);
    const float sp_adiv = softplus_f(adiv[0]);
    const float sa0 = softplus_f(a_vector[0]);
    const float sa1 = softplus_f(a_vector[1]);
    const float sa2 = softplus_f(a_vector[2]);
    const float sa3 = softplus_f(a_vector[3]);
    float c0 = softplus_f(c_vector[0]);
    float c1 = softplus_f(c_vector[1]);
    float c2 = softplus_f(c_vector[2]);
    float c3 = softplus_f(c_vector[3]);
    const float cs = fabsf(c0) + fabsf(c1) + fabsf(c2) + fabsf(c3);
    const float cinv = 1.0f / cs;
    c0 *= cinv; c1 *= cinv; c2 *= cinv; c3 *= cinv;

    const int stride = gridDim.x * blockDim.x;
    for (int e = blockIdx.x * blockDim.x + threadIdx.x; e < E; e += stride) {
        const int i = idx_i[e];
        const int j = idx_j[e];
        const float zi = Z[i];
        const float zj = Z[j];
        const float x  = r_ij[3 * e + 0];
        const float yy = r_ij[3 * e + 1];
        const float zz = r_ij[3 * e + 2];
        const float d = sqrtf(x * x + yy * yy + zz * zz);

        const float u = d * (1.0f / RCUT);
        const float u3 = u * u * u;
        float fc = 1.0f + u3 * (-10.0f + u * (15.0f - 6.0f * u));
        fc = (d < RCUT) ? fc : 0.0f;

        const float a = (__powf(zi, sp_apow) + __powf(zj, sp_apow)) * sp_adiv;
        const float ad = a * d;
        const float ft = c0 * __expf(-sa0 * ad) + c1 * __expf(-sa1 * ad)
                       + c2 * __expf(-sa2 * ad) + c3 * __expf(-sa3 * ad);

        const float ee = KEHALF * ft * fc * zi * zj / d;
        atomicAdd(&bins[idx_m[i]], ee);
    }

    __syncthreads();
    for (int b = threadIdx.x; b < NUM_MOL; b += blockDim.x) {
        const float v = bins[b];
        if (v != 0.0f) atomicAdd(&y[b], v);
    }
}

extern "C" void kernel_launch(void* const* d_in, const int* in_sizes, int n_in,
                              void* d_out, int out_size, void* d_ws, size_t ws_size,
                              hipStream_t stream) {
    // setup_inputs order: Z, r_ij, idx_i, idx_j, idx_m, adiv, apow, a_vector, c_vector
    const float* Z        = (const float*)d_in[0];
    const float* r_ij     = (const float*)d_in[1];
    const int*   idx_i    = (const int*)d_in[2];
    const int*   idx_j    = (const int*)d_in[3];
    const int*   idx_m    = (const int*)d_in[4];
    const float* adiv     = (const float*)d_in[5];
    const float* apow     = (const float*)d_in[6];
    const float* a_vector = (const float*)d_in[7];
    const float* c_vector = (const float*)d_in[8];
    float* y = (float*)d_out;

    const int N = in_sizes[0];
    const int E = in_sizes[1] / 3;

    // d_out is poisoned 0xAA before every launch -> zero it (graph-safe memset node)
    hipMemsetAsync(y, 0, (size_t)out_size * sizeof(float), stream);

    const size_t atab_bytes = (size_t)N * sizeof(float4);
    if (ws_size >= atab_bytes) {
        float4* atab = (float4*)d_ws;
        zbl_prep_kernel<<<(N + 255) / 256, 256, 0, stream>>>(Z, idx_m, apow, atab, N);
        zbl_edge_kernel<<<1024, 256, 0, stream>>>(r_ij, idx_i, idx_j, atab,
                                                  adiv, a_vector, c_vector, y, E);
    } else {
        zbl_edge_kernel_nows<<<1024, 256, 0, stream>>>(r_ij, idx_i, idx_j, Z, idx_m,
                                                       adiv, apow, a_vector, c_vector, y, E);
    }
}